// Round 6
// baseline (890.601 us; speedup 1.0000x reference)
//
#include <hip/hip_runtime.h>
#include <hip/hip_bf16.h>
#include <math.h>

// Problem constants (from reference setup_inputs)
#define Bq   16
#define Sq   1024
#define Hq   1024
#define Oq   256
#define Lq   4
#define NHq  8
#define DHq  128
#define Mq   (Bq*Sq)      // 16384 rows
#define HHq  (Hq*Hq)      // 1048576
#define NCc  32           // scan chunks
#define CTc  32           // timesteps per chunk

typedef __bf16 bf16x8 __attribute__((ext_vector_type(8)));
typedef float  f32x4  __attribute__((ext_vector_type(4)));

__device__ __forceinline__ float bf2f(unsigned int u) {
    union { unsigned int i; float f; } x; x.i = u << 16; return x.f;
}
__device__ __forceinline__ unsigned short f2bf(float f) {
    union { float f; unsigned int i; } x; x.f = f;
    unsigned int r = x.i + 0x7fffu + ((x.i >> 16) & 1u);   // RNE
    return (unsigned short)(r >> 16);
}
__device__ __forceinline__ float sigm(float x) { return 1.f / (1.f + __expf(-x)); }

__device__ __forceinline__ void gl2lds16(const unsigned short* g, unsigned short* l) {
    __builtin_amdgcn_global_load_lds((const __attribute__((address_space(1))) void*)g,
                                     (__attribute__((address_space(3))) void*)l, 16, 0, 0);
}

// ---------------- fp32 -> bf16 convert ----------------
__global__ void cvt_kernel(const float* __restrict__ src, unsigned short* __restrict__ dst, int n) {
    int i = blockIdx.x * 256 + threadIdx.x;
    if (i < n) dst[i] = f2bf(src[i]);
}

// ---------------- fused weight convert: Wcat[l][f;i;h][H][H] ----------------
__global__ void cvtW_kernel(const float* __restrict__ Wf, const float* __restrict__ Wi,
                            const float* __restrict__ Wh, unsigned short* __restrict__ Wcat) {
    int i = blockIdx.x * 256 + threadIdx.x;     // L*3*HH
    int l = (i >> 20) / 3;
    int r = i - l * 3 * HHq;
    int g = r >> 20; int j = r & (HHq - 1);
    const float* s = (g == 0) ? Wf : (g == 1) ? Wi : Wh;
    Wcat[i] = f2bf(s[(size_t)l * HHq + j]);
}

// ---------------- assemble per-layer [bf;bi;bh] bias (L x 3072) ----------------
__global__ void bias3_kernel(const float* __restrict__ bf_, const float* __restrict__ bi_,
                             const float* __restrict__ bh_, float* __restrict__ out) {
    int i = blockIdx.x * 256 + threadIdx.x;          // L*3H = 12288
    int l = i / (3*Hq); int r = i % (3*Hq); int g = r >> 10; int j = r & (Hq-1);
    const float* s = (g == 0) ? bf_ : (g == 1) ? bi_ : bh_;
    out[i] = s[l*Hq + j];
}

// ---------------- FUSED 3-gate GEMM + gate math ----------------
// R6: PHASED compute (T3 port). Round-5 post-mortem: tile growth moved util
// 35.5 -> 37% only; the one-phase bulk-read-then-bulk-MFMA rhythm is the cap
// (LDS burst ~1000-1300cyc with MFMA idle, then MFMA burst). The 256² 8-phase
// template (same frag pattern, WORSE compute:read ratio) hits 62% -- the
// catalog's regime-gate: fine phase interleave is the lever (m196/m218/m230).
// This round: round-5 kernel with COMPUTE split into 3 barrier-bracketed
// phases (one per gate): {reads; lgkmcnt(0); setprio1; 16 MFMA; setprio0;
// s_barrier}. 4 uniform barriers/iter. Staging machinery, swizzles, ring-4,
// vmcnt ladder 10/5/0, epilogue BYTE-IDENTICAL to round-5 (verified).
// Ring safety: slot (t+2)&3 overwritten at iter-t STAGE; its last reads were
// in iter t-2's phases, and the issuing wave has passed >=5 barriers since
// (iter t-1's four + iter t's pre-barrier precede any iter-t write landing
// before... pre-barrier follows STAGE issue, but slot release needs only the
// issuing wave to have passed ONE barrier that every reader reached after its
// last read -- iter t-1's first barrier qualifies). Accumulation order
// unchanged (32 x BK=32) -> same numerics.
__global__ __launch_bounds__(512, 1)
void gemm_gate_kernel(const unsigned short* __restrict__ A, const unsigned short* __restrict__ Wl,
                      const float* __restrict__ bias3, unsigned short* __restrict__ FPo,
                      unsigned short* __restrict__ ADDo)
{
    const int K = Hq;
    __shared__ unsigned short lds[4 * 20480];   // 160 KB: 4 slots x (A 8192 + W 12288 shorts)
    const int tid  = threadIdx.x;

    // XCD swizzle: 512 blocks; per XCD 8 bm x 8 cb, cb fastest -> A-tile (512KB)
    // shared by 8 consecutive blocks on one XCD.
    const int lid = blockIdx.x;               // 512 blocks
    const int xcd = lid & 7;
    const int s   = lid >> 3;                 // 0..63
    const int bm  = xcd * 8 + (s >> 3);       // 0..63 (256-row blocks)
    const int cb  = s & 7;                    // channel block (128 channels)

    const int wid  = tid >> 6, lane = tid & 63;
    const int wm   = (wid >> 2) * 128;        // 0/128
    const int wn   = (wid & 3) * 32;          // 0/32/64/96 within each gate
    const int l15  = lane & 15, quad = lane >> 4;

    const unsigned short* Ag = A + (size_t)(bm*256) * K;

    // --- staging offsets (verified swizzle: key=(lane>>3)&3, phys chunk lane&3) ---
    const int lr   = lane >> 2;               // 0..15 row within 16-row issue
    const int gc   = (lane & 3) ^ ((lane >> 3) & 3);
    // A: 256 rows; wave w stages rows [w*32, w*32+32) in 2 issues of 16 rows
    int offA[2], ldsA[2];
    #pragma unroll
    for (int q = 0; q < 2; ++q) {
        int ra = wid*32 + q*16 + lr;
        offA[q] = ra * K + gc*8;
        ldsA[q] = (wid*32 + q*16) * 32;
    }
    // W: 384 LDS rows (3 gates x 128); wave w stages [w*48, w*48+48) in 3 issues
    // of 16. Row rw -> gate g=rw>>7, row-in-gate nr=rw&127.
    int offW[3], ldsW[3];
    #pragma unroll
    for (int q = 0; q < 3; ++q) {
        int rw = wid*48 + q*16 + lr;
        int g  = rw >> 7;
        int nr = rw & 127;
        offW[q] = g * HHq + (cb*128 + nr) * K + gc*8;
        ldsW[q] = 8192 + (wid*48 + q*16) * 32;
    }

    // fragment read swizzle: phys chunk = quad ^ ((l15>>1)&3)
    const int crd = quad ^ ((l15 >> 1) & 3);

    f32x4 acc[3][8][2] = {};                  // 192-reg accumulator

    auto STAGE = [&](int kt, int slot) {
        const int kof = kt << 5;
        unsigned short* Sb = &lds[slot * 20480];
        #pragma unroll
        for (int q = 0; q < 2; ++q) gl2lds16(Ag + offA[q] + kof, Sb + ldsA[q]);
        #pragma unroll
        for (int q = 0; q < 3; ++q) gl2lds16(Wl + offW[q] + kof, Sb + ldsW[q]);
    };

    // Phased compute: 3 phases, each {reads, lgkmcnt(0), setprio MFMA cluster,
    // barrier}. Phase 0 additionally reads the 8 A-frags.
    auto COMPUTE_PHASED = [&](int slot) {
        const unsigned short* Sa = &lds[slot * 20480];
        const unsigned short* Sw = Sa + 8192;
        bf16x8 af[8];
        #pragma unroll
        for (int q = 0; q < 8; ++q)
            af[q] = *(const bf16x8*)&Sa[(wm + q*16 + l15)*32 + crd*8];
        #pragma unroll
        for (int g = 0; g < 3; ++g) {
            bf16x8 wf0 = *(const bf16x8*)&Sw[(g*128 + wn +      l15)*32 + crd*8];
            bf16x8 wf1 = *(const bf16x8*)&Sw[(g*128 + wn + 16 + l15)*32 + crd*8];
            asm volatile("s_waitcnt lgkmcnt(0)" ::: "memory");
            __builtin_amdgcn_sched_barrier(0);
            __builtin_amdgcn_s_setprio(1);
            #pragma unroll
            for (int tm = 0; tm < 8; ++tm) {
                acc[g][tm][0] = __builtin_amdgcn_mfma_f32_16x16x32_bf16(af[tm], wf0, acc[g][tm][0], 0, 0, 0);
                acc[g][tm][1] = __builtin_amdgcn_mfma_f32_16x16x32_bf16(af[tm], wf1, acc[g][tm][1], 0, 0, 0);
            }
            __builtin_amdgcn_s_setprio(0);
            __builtin_amdgcn_sched_barrier(0);
            __builtin_amdgcn_s_barrier();
            asm volatile("" ::: "memory");
        }
    };

    const int niter = K >> 5;                 // 32 K-tiles

    // prologue: tiles 0,1 in flight
    STAGE(0, 0);
    STAGE(1, 1);

    // main loop: counted vmcnt(10) = tiles t+1,t+2 (5 loads each) stay in flight
    for (int t = 0; t < niter - 2; ++t) {
        STAGE(t + 2, (t + 2) & 3);
        asm volatile("s_waitcnt vmcnt(10) lgkmcnt(0)" ::: "memory");
        __builtin_amdgcn_s_barrier();
        asm volatile("" ::: "memory");
        COMPUTE_PHASED(t & 3);
    }
    // tail: drain 5 -> 0
    asm volatile("s_waitcnt vmcnt(5) lgkmcnt(0)" ::: "memory");
    __builtin_amdgcn_s_barrier();
    asm volatile("" ::: "memory");
    COMPUTE_PHASED((niter - 2) & 3);
    asm volatile("s_waitcnt vmcnt(0) lgkmcnt(0)" ::: "memory");
    __builtin_amdgcn_s_barrier();
    asm volatile("" ::: "memory");
    COMPUTE_PHASED((niter - 1) & 3);

    // epilogue: gate math + bf16 FP/ADD write (C layout: row=quad*4+r, col=l15)
    #pragma unroll
    for (int tm = 0; tm < 8; ++tm) {
        int row0 = bm*256 + wm + tm*16 + quad*4;
        #pragma unroll
        for (int tn = 0; tn < 2; ++tn) {
            int col = cb*128 + wn + tn*16 + l15;
            float bf_ = bias3[col], bi_ = bias3[Hq + col], bh_ = bias3[2*Hq + col];
            #pragma unroll
            for (int r = 0; r < 4; ++r) {
                float f  = sigm(acc[0][tm][tn][r] + bf_);
                float i  = sigm(acc[1][tm][tn][r] + bi_);
                float ht = acc[2][tm][tn][r] + bh_;
                float rd = 1.f / (f + i);
                size_t off = (size_t)(row0 + r) * Hq + col;
                FPo[off]  = f2bf(f * rd);
                ADDo[off] = f2bf(i * rd * ht);
            }
        }
    }
}

// ---------------- plain bf16 GEMM (used for KV projection) ----------------
// Round-3-verified ring-4 counted-vmcnt pipeline (slot = A 8KB + W 8KB =
// 16KB, ring = 64KB -> 2 blocks/CU; 4 loads/tile/thread -> vmcnt(8)).
__global__ __launch_bounds__(256, 2)
void gemm_bt_kernel(const unsigned short* __restrict__ A, const unsigned short* __restrict__ W,
                    const float* __restrict__ bias, unsigned short* __restrict__ C,
                    int N, int K, int nbn)
{
    __shared__ unsigned short lds[4 * 8192];    // 64 KB: 4 slots x (A 4096 + W 4096 shorts)
    const int tid  = threadIdx.x;

    const int lid = blockIdx.x;
    const int xcd = lid & 7;
    const int s   = lid >> 3;
    const int bm  = xcd * 16 + s / nbn;
    const int bn  = s % nbn;

    const int wid  = tid >> 6, lane = tid & 63;
    const int wm   = (wid >> 1) * 64, wn = (wid & 1) * 64;
    const int l15  = lane & 15, quad = lane >> 4;

    const unsigned short* Ag = A + (size_t)(bm*128) * K;
    const unsigned short* Wg = W + (size_t)(bn*128) * K;

    const int r0   = wid*32 + (lane >> 2);
    const int cst  = (lane & 3) ^ ((r0 >> 1) & 3);
    const int g0   = r0 * K + cst*8;
    const int g1   = (r0 + 16) * K + cst*8;
    const int lofs0 = wid*1024;
    const int lofs1 = wid*1024 + 512;

    const int crd = quad ^ ((l15 >> 1) & 3);

    f32x4 acc[4][4] = {};

    auto STAGE = [&](int kt, int slot) {
        const int kof = kt << 5;
        unsigned short* Sb = &lds[slot * 8192];
        gl2lds16(Ag + g0 + kof, Sb + lofs0);
        gl2lds16(Ag + g1 + kof, Sb + lofs1);
        gl2lds16(Wg + g0 + kof, Sb + 4096 + lofs0);
        gl2lds16(Wg + g1 + kof, Sb + 4096 + lofs1);
    };

    auto COMPUTE = [&](int slot) {
        const unsigned short* Sa = &lds[slot * 8192];
        const unsigned short* Sw = Sa + 4096;
        bf16x8 af[4], wf[4];
        #pragma unroll
        for (int t = 0; t < 4; ++t) {
            af[t] = *(const bf16x8*)&Sa[(wm + t*16 + l15)*32 + crd*8];
            wf[t] = *(const bf16x8*)&Sw[(wn + t*16 + l15)*32 + crd*8];
        }
        __builtin_amdgcn_s_setprio(1);
        #pragma unroll
        for (int tm = 0; tm < 4; ++tm)
            #pragma unroll
            for (int tn = 0; tn < 4; ++tn)
                acc[tm][tn] = __builtin_amdgcn_mfma_f32_16x16x32_bf16(af[tm], wf[tn], acc[tm][tn], 0, 0, 0);
        __builtin_amdgcn_s_setprio(0);
    };

    const int niter = K >> 5;

    STAGE(0, 0);
    STAGE(1, 1);

    for (int it = 0; it < niter - 2; ++it) {
        STAGE(it + 2, (it + 2) & 3);
        asm volatile("s_waitcnt vmcnt(8) lgkmcnt(0)" ::: "memory");
        __builtin_amdgcn_s_barrier();
        asm volatile("" ::: "memory");
        COMPUTE(it & 3);
    }
    asm volatile("s_waitcnt vmcnt(4) lgkmcnt(0)" ::: "memory");
    __builtin_amdgcn_s_barrier();
    asm volatile("" ::: "memory");
    COMPUTE((niter - 2) & 3);
    asm volatile("s_waitcnt vmcnt(0) lgkmcnt(0)" ::: "memory");
    __builtin_amdgcn_s_barrier();
    asm volatile("" ::: "memory");
    COMPUTE((niter - 1) & 3);

    #pragma unroll
    for (int tm = 0; tm < 4; ++tm) {
        int row0 = bm*128 + wm + tm*16 + quad*4;
        #pragma unroll
        for (int tn = 0; tn < 4; ++tn) {
            int col = bn*128 + wn + tn*16 + l15;
            float bv = bias[col];
            #pragma unroll
            for (int r = 0; r < 4; ++r)
                C[(size_t)(row0 + r) * N + col] = f2bf(acc[tm][tn][r] + bv);
        }
    }
}

// ---------------- chunked scan over precomputed FP/ADD ----------------
// Pass A: per (b,chunk,j-pair): P = prod fp, Asum = local scan from h=0.
__global__ __launch_bounds__(256)
void scan_sum_kernel(const unsigned short* __restrict__ FP, const unsigned short* __restrict__ AD,
                     float* __restrict__ Ps, float* __restrict__ Asum) {
    int bid = blockIdx.x;                    // B*NC*2 = 1024
    int tid = threadIdx.x;
    int b = bid >> 6; int r = bid & 63; int chunk = r >> 1; int jb = r & 1;
    int j = jb*512 + tid*2;
    size_t base = ((size_t)(b*Sq + chunk*CTc)) * Hq + j;
    float P0 = 1.f, P1 = 1.f, A0 = 0.f, A1 = 0.f;
    for (int s = 0; s < CTc; ++s) {
        size_t ro = base + (size_t)s * Hq;
        unsigned int uf = *(const unsigned int*)(FP + ro);
        unsigned int ua = *(const unsigned int*)(AD + ro);
        float fp0 = bf2f(uf & 0xffffu), fp1 = bf2f(uf >> 16);
        float ad0 = bf2f(ua & 0xffffu), ad1 = bf2f(ua >> 16);
        P0 *= fp0; A0 = fp0 * A0 + ad0;
        P1 *= fp1; A1 = fp1 * A1 + ad1;
    }
    int oi = (b*NCc + chunk)*Hq + j;
    Ps[oi] = P0; Ps[oi+1] = P1;
    Asum[oi] = A0; Asum[oi+1] = A1;
}

// Pass B: chunk-level prefix. h entering chunk c stored to Hb.
__global__ void scan_base_kernel(const float* __restrict__ Ps, const float* __restrict__ Asum,
                                 float* __restrict__ Hb) {
    int t = blockIdx.x * 256 + threadIdx.x;  // B*H = 16384
    int b = t >> 10, j = t & 1023;
    float h = 0.f;
    for (int c = 0; c < NCc; ++c) {
        int idx = (b*NCc + c)*Hq + j;
        Hb[idx] = h;
        h = Ps[idx] * h + Asum[idx];
    }
}

// Pass C: re-read FP/ADD, scan with correct init, write bf16 h.
__global__ __launch_bounds__(256)
void scan_out_kernel(const unsigned short* __restrict__ FP, const unsigned short* __restrict__ AD,
                     const float* __restrict__ Hb, unsigned short* __restrict__ Ho) {
    int bid = blockIdx.x;                    // B*NC*2 = 1024
    int tid = threadIdx.x;
    int b = bid >> 6; int r = bid & 63; int chunk = r >> 1; int jb = r & 1;
    int j = jb*512 + tid*2;
    size_t base = ((size_t)(b*Sq + chunk*CTc)) * Hq + j;
    int oi = (b*NCc + chunk)*Hq + j;
    float h0 = Hb[oi], h1 = Hb[oi+1];
    for (int s = 0; s < CTc; ++s) {
        size_t ro = base + (size_t)s * Hq;
        unsigned int uf = *(const unsigned int*)(FP + ro);
        unsigned int ua = *(const unsigned int*)(AD + ro);
        h0 = bf2f(uf & 0xffffu) * h0 + bf2f(ua & 0xffffu);
        h1 = bf2f(uf >> 16)     * h1 + bf2f(ua >> 16);
        unsigned int packed = (unsigned int)f2bf(h0) | ((unsigned int)f2bf(h1) << 16);
        *(unsigned int*)(Ho + ro) = packed;
    }
}

// ---------------- extract last-position activations as fp32 ----------------
__global__ void xlast_kernel(const unsigned short* __restrict__ act, float* __restrict__ xl) {
    int i = blockIdx.x * 256 + threadIdx.x;  // B*H
    int b = i >> 10, j = i & 1023;
    xl[i] = bf2f((unsigned int)act[((size_t)(b*Sq + Sq-1)) * Hq + j]);
}

// ---------------- wave-per-row GEMV: out[b,n] = W[n,:].x[b,:] + bias[n] (+resid[b,n]) ----------------
__global__ __launch_bounds__(256)
void gemv_kernel(const float* __restrict__ W, const float* __restrict__ xv,
                 const float* __restrict__ bias, const float* __restrict__ resid,
                 float* __restrict__ out, int N) {
    int b = blockIdx.x;
    int w = threadIdx.x >> 6, lane = threadIdx.x & 63;
    int n = blockIdx.y*4 + w;
    __shared__ float xs[Hq];
    *(float4*)&xs[threadIdx.x*4] = *(const float4*)&xv[(size_t)b*Hq + threadIdx.x*4];
    __syncthreads();
    const float4* wr = (const float4*)(W + (size_t)n * Hq);
    float a = 0.f;
    #pragma unroll
    for (int c = 0; c < 4; ++c) {
        float4 wv = wr[c*64 + lane];
        float4 x4 = *(const float4*)&xs[c*256 + lane*4];
        a += wv.x*x4.x + wv.y*x4.y + wv.z*x4.z + wv.w*x4.w;
    }
    #pragma unroll
    for (int st = 32; st > 0; st >>= 1) a += __shfl_xor(a, st, 64);
    if (lane == 0) out[(size_t)b*N + n] = a + bias[n] + (resid ? resid[(size_t)b*Hq + n] : 0.f);
}

// ---------------- attention for the single last-position query ----------------
__global__ __launch_bounds__(1024)
void attn_kernel(const unsigned short* __restrict__ KV,
                 const float* __restrict__ q, float* __restrict__ o) {
    int b = blockIdx.x >> 3, nh = blockIdx.x & 7;
    int tid = threadIdx.x;
    __shared__ float qs[DHq];
    __shared__ float p[Sq];
    __shared__ float redw[16];
    __shared__ float red2[16*DHq];
    if (tid < DHq) qs[tid] = q[b*Hq + nh*DHq + tid] * 0.08838834764831845f;
    __syncthreads();

    const int g = tid >> 4, l = tid & 15;
    const unsigned short* Kb = KV + (size_t)b*Sq*2048 + nh*DHq;
    float lmax = -1e30f;
    #pragma unroll 4
    for (int it = 0; it < 16; ++it) {
        int s = it*64 + g;
        union { uint4 v; unsigned short u[8]; } kk;
        kk.v = *(const uint4*)(Kb + (size_t)s*2048 + l*8);
        float a = 0.f;
        #pragma unroll
        for (int j = 0; j < 8; ++j) a += bf2f((unsigned int)kk.u[j]) * qs[l*8 + j];
        a += __shfl_xor(a, 1, 16);
        a += __shfl_xor(a, 2, 16);
        a += __shfl_xor(a, 4, 16);
        a += __shfl_xor(a, 8, 16);
        if (l == 0) p[s] = a;
        lmax = fmaxf(lmax, a);
    }
    #pragma unroll
    for (int st = 32; st > 0; st >>= 1) lmax = fmaxf(lmax, __shfl_xor(lmax, st, 64));
    if ((tid & 63) == 0) redw[tid >> 6] = lmax;
    __syncthreads();
    float mx = redw[0];
    #pragma unroll
    for (int i = 1; i < 16; ++i) mx = fmaxf(mx, redw[i]);

    float e = __expf(p[tid] - mx);
    float ls = e;
    #pragma unroll
    for (int st = 32; st > 0; st >>= 1) ls += __shfl_xor(ls, st, 64);
    __syncthreads();
    p[tid] = e;
    if ((tid & 63) == 0) redw[tid >> 6] = ls;
    __syncthreads();
    float ssum = 0.f;
    #pragma unroll
    for (int i = 0; i < 16; ++i) ssum += redw[i];
    float inv = 1.f / ssum;

    int d2 = (tid & 63) * 2, sb = tid >> 6;
    const unsigned short* Vb = KV + (size_t)b*Sq*2048 + 1024 + nh*DHq + d2;
    float a0 = 0.f, a1 = 0.f;
    for (int s = sb*64; s < sb*64 + 64; ++s) {
        unsigned int vv = *(const unsigned int*)(Vb + (size_t)s*2048);
        float pw = p[s];
        a0 += pw * bf2f(vv & 0xffffu);
        a1 += pw * bf2f(vv >> 16);
    }
    red2[sb*DHq + d2] = a0;
    red2[sb*DHq + d2 + 1] = a1;
    __syncthreads();
    if (tid < DHq) {
        float a = 0.f;
        #pragma unroll
        for (int i = 0; i < 16; ++i) a += red2[i*DHq + tid];
        o[b*Hq + nh*DHq + tid] = a * inv;
    }
}

extern "C" void kernel_launch(void* const* d_in, const int* in_sizes, int n_in,
                              void* d_out, int out_size, void* d_ws, size_t ws_size,
                              hipStream_t stream) {
    const float* x        = (const float*)d_in[0];
    const float* Wf       = (const float*)d_in[1];
    const float* bfv      = (const float*)d_in[2];
    const float* Wi       = (const float*)d_in[3];
    const float* biv      = (const float*)d_in[4];
    const float* Wh       = (const float*)d_in[5];
    const float* bhv      = (const float*)d_in[6];
    const float* in_proj_w= (const float*)d_in[7];
    const float* in_proj_b= (const float*)d_in[8];
    const float* out_w    = (const float*)d_in[9];
    const float* out_b    = (const float*)d_in[10];
    const float* fc_w     = (const float*)d_in[11];
    const float* fc_b     = (const float*)d_in[12];
    float* outp = (float*)d_out;

    // workspace carve (~160 MB)
    char* p = (char*)d_ws;
    auto alloc = [&](size_t bytes) -> void* {
        void* r = (void*)p; p += (bytes + 255) & ~(size_t)255; return r;
    };
    unsigned short* Wcat = (unsigned short*)alloc((size_t)Lq*3*HHq*2);  // 24 MB
    unsigned short* Wkv  = (unsigned short*)alloc((size_t)2048*Hq*2);   //  4 MB
    float*          Bias3= (float*)alloc((size_t)Lq*3*Hq*4);            // 48 KB
    unsigned short* actA = (unsigned short*)alloc((size_t)Mq*Hq*2);     // 32 MB
    unsigned short* actB = (unsigned short*)alloc((size_t)Mq*Hq*2);     // 32 MB
    unsigned short* FPg  = (unsigned short*)alloc((size_t)Mq*Hq*2);     // 32 MB
    unsigned short* ADDg = (unsigned short*)alloc((size_t)Mq*Hq*2);     // 32 MB (contiguous after FPg)
    float* Ps   = (float*)alloc((size_t)Bq*NCc*Hq*4);                   //  2 MB
    float* Asum = (float*)alloc((size_t)Bq*NCc*Hq*4);                   //  2 MB
    float* Hb   = (float*)alloc((size_t)Bq*NCc*Hq*4);                   //  2 MB
    unsigned short* KV = FPg;  // alias: 64 MB (FPg+ADDg), used only after layers done
    float* xl   = (float*)alloc((size_t)Bq*Hq*4);
    float* qbuf = (float*)alloc((size_t)Bq*Hq*4);
    float* obuf = (float*)alloc((size_t)Bq*Hq*4);
    float* rbuf = (float*)alloc((size_t)Bq*Hq*4);

    // --- conversions ---
    cvt_kernel<<<Mq*Hq/256, 256, 0, stream>>>(x, actA, Mq*Hq);
    cvtW_kernel<<<Lq*3*HHq/256, 256, 0, stream>>>(Wf, Wi, Wh, Wcat);
    cvt_kernel<<<2048*Hq/256, 256, 0, stream>>>(in_proj_w + (size_t)Hq*Hq, Wkv, 2048*Hq);
    bias3_kernel<<<(Lq*3*Hq)/256, 256, 0, stream>>>(bfv, biv, bhv, Bias3);

    // --- minLSTM layers ---
    unsigned short* cur = actA;
    unsigned short* nxt = actB;
    for (int l = 0; l < Lq; ++l) {
        gemm_gate_kernel<<<(Mq/256)*(Hq/128), 512, 0, stream>>>(
            cur, Wcat + (size_t)l*3*HHq, Bias3 + l*3*Hq, FPg, ADDg);
        scan_sum_kernel<<<Bq*NCc*2, 256, 0, stream>>>(FPg, ADDg, Ps, Asum);
        scan_base_kernel<<<Bq*Hq/256, 256, 0, stream>>>(Ps, Asum, Hb);
        scan_out_kernel<<<Bq*NCc*2, 256, 0, stream>>>(FPg, ADDg, Hb, nxt);
        unsigned short* t = cur; cur = nxt; nxt = t;
    }

    // --- attention (only last-position query matters) ---
    gemm_bt_kernel<<<(Mq/128)*(2048/128), 256, 0, stream>>>(
        cur, Wkv, in_proj_b + Hq, KV, 2048, Hq, 2048/128);
    xlast_kernel<<<Bq*Hq/256, 256, 0, stream>>>(cur, xl);
    gemv_kernel<<<dim3(Bq, Hq/4), 256, 0, stream>>>(in_proj_w, xl, in_proj_b, nullptr, qbuf, Hq);
    attn_kernel<<<Bq*NHq, 1024, 0, stream>>>(KV, qbuf, obuf);
    gemv_kernel<<<dim3(Bq, Hq/4), 256, 0, stream>>>(out_w, obuf, out_b, xl, rbuf, Hq);
    gemv_kernel<<<dim3(Bq, Oq/4), 256, 0, stream>>>(fc_w, rbuf, fc_b, nullptr, outp, Oq);
}

// Round 7
// 815.414 us; speedup vs baseline: 1.0922x; 1.0922x over previous
//
#include <hip/hip_runtime.h>
#include <hip/hip_bf16.h>
#include <math.h>

// Problem constants (from reference setup_inputs)
#define Bq   16
#define Sq   1024
#define Hq   1024
#define Oq   256
#define Lq   4
#define NHq  8
#define DHq  128
#define Mq   (Bq*Sq)      // 16384 rows
#define HHq  (Hq*Hq)      // 1048576
#define NCc  32           // scan chunks
#define CTc  32           // timesteps per chunk

typedef __bf16 bf16x8 __attribute__((ext_vector_type(8)));
typedef float  f32x4  __attribute__((ext_vector_type(4)));

__device__ __forceinline__ float bf2f(unsigned int u) {
    union { unsigned int i; float f; } x; x.i = u << 16; return x.f;
}
__device__ __forceinline__ unsigned short f2bf(float f) {
    union { float f; unsigned int i; } x; x.f = f;
    unsigned int r = x.i + 0x7fffu + ((x.i >> 16) & 1u);   // RNE
    return (unsigned short)(r >> 16);
}
__device__ __forceinline__ float sigm(float x) { return 1.f / (1.f + __expf(-x)); }

__device__ __forceinline__ void gl2lds16(const unsigned short* g, unsigned short* l) {
    __builtin_amdgcn_global_load_lds((const __attribute__((address_space(1))) void*)g,
                                     (__attribute__((address_space(3))) void*)l, 16, 0, 0);
}

// ---------------- fp32 -> bf16 convert ----------------
__global__ void cvt_kernel(const float* __restrict__ src, unsigned short* __restrict__ dst, int n) {
    int i = blockIdx.x * 256 + threadIdx.x;
    if (i < n) dst[i] = f2bf(src[i]);
}

// ---------------- fused weight convert: Wcat[l][f;i;h][H][H] ----------------
__global__ void cvtW_kernel(const float* __restrict__ Wf, const float* __restrict__ Wi,
                            const float* __restrict__ Wh, unsigned short* __restrict__ Wcat) {
    int i = blockIdx.x * 256 + threadIdx.x;     // L*3*HH
    int l = (i >> 20) / 3;
    int r = i - l * 3 * HHq;
    int g = r >> 20; int j = r & (HHq - 1);
    const float* s = (g == 0) ? Wf : (g == 1) ? Wi : Wh;
    Wcat[i] = f2bf(s[(size_t)l * HHq + j]);
}

// ---------------- assemble per-layer [bf;bi;bh] bias (L x 3072) ----------------
__global__ void bias3_kernel(const float* __restrict__ bf_, const float* __restrict__ bi_,
                             const float* __restrict__ bh_, float* __restrict__ out) {
    int i = blockIdx.x * 256 + threadIdx.x;          // L*3H = 12288
    int l = i / (3*Hq); int r = i % (3*Hq); int g = r >> 10; int j = r & (Hq-1);
    const float* s = (g == 0) ? bf_ : (g == 1) ? bi_ : bh_;
    out[i] = s[l*Hq + j];
}

// ---------------- FUSED 3-gate GEMM + gate math + chunk-scan summaries ----------------
// R7: K-loop = EXACT round-5 one-phase ring-4 (proven best: 121us, 852 TF;
// both phased variants regressed -> this structure's util is accepted).
// New in this round (epilogue only):
//  (a) fp/add written INTERLEAVED as one u32/element to FPAD. Old layout: 2x
//      ushort scattered -> 32B row-segments -> WRITE_SIZE 97.5MB vs 64MB
//      logical (1.52x partial-line leak). Now per (tm,r) the wave's two
//      tn-stores fill exactly one aligned 128B line. Also halves store count.
//  (b) scan_sum FUSED here: each block holds 8 complete chunks x 128 cols, so
//      per-chunk (P = prod fp, A = affine sum) is computed in-register:
//      in-lane over r (time order), ordered cross-quad Hillis-Steele via
//      __shfl_up (composition associative, order preserved: quad ascending =
//      row ascending = time). Values are bf16-roundtripped first so summaries
//      match old scan_sum's inputs; association diffs ~1e-7 << 1e-3 tol.
//      Eliminates 4x scan_sum dispatches (each re-read all 64MB of FP/ADD).
__global__ __launch_bounds__(512, 1)
void gemm_gate_kernel(const unsigned short* __restrict__ A, const unsigned short* __restrict__ Wl,
                      const float* __restrict__ bias3, unsigned int* __restrict__ FA,
                      float* __restrict__ Ps, float* __restrict__ Asum)
{
    const int K = Hq;
    __shared__ unsigned short lds[4 * 20480];   // 160 KB: 4 slots x (A 8192 + W 12288 shorts)
    const int tid  = threadIdx.x;

    // XCD swizzle: 512 blocks; per XCD 8 bm x 8 cb, cb fastest.
    const int lid = blockIdx.x;               // 512 blocks
    const int xcd = lid & 7;
    const int s   = lid >> 3;                 // 0..63
    const int bm  = xcd * 8 + (s >> 3);       // 0..63 (256-row blocks)
    const int cb  = s & 7;                    // channel block (128 channels)

    const int wid  = tid >> 6, lane = tid & 63;
    const int wm   = (wid >> 2) * 128;        // 0/128
    const int wn   = (wid & 3) * 32;          // 0/32/64/96 within each gate
    const int l15  = lane & 15, quad = lane >> 4;

    const unsigned short* Ag = A + (size_t)(bm*256) * K;

    // --- staging offsets (verified swizzle: key=(lane>>3)&3, phys chunk lane&3) ---
    const int lr   = lane >> 2;               // 0..15 row within 16-row issue
    const int gc   = (lane & 3) ^ ((lane >> 3) & 3);
    // A: 256 rows; wave w stages rows [w*32, w*32+32) in 2 issues of 16 rows
    int offA[2], ldsA[2];
    #pragma unroll
    for (int q = 0; q < 2; ++q) {
        int ra = wid*32 + q*16 + lr;
        offA[q] = ra * K + gc*8;
        ldsA[q] = (wid*32 + q*16) * 32;
    }
    // W: 384 LDS rows (3 gates x 128); wave w stages [w*48, w*48+48) in 3 issues.
    int offW[3], ldsW[3];
    #pragma unroll
    for (int q = 0; q < 3; ++q) {
        int rw = wid*48 + q*16 + lr;
        int g  = rw >> 7;
        int nr = rw & 127;
        offW[q] = g * HHq + (cb*128 + nr) * K + gc*8;
        ldsW[q] = 8192 + (wid*48 + q*16) * 32;
    }

    // fragment read swizzle: phys chunk = quad ^ ((l15>>1)&3)
    const int crd = quad ^ ((l15 >> 1) & 3);

    f32x4 acc[3][8][2] = {};                  // 192-reg accumulator

    auto STAGE = [&](int kt, int slot) {
        const int kof = kt << 5;
        unsigned short* Sb = &lds[slot * 20480];
        #pragma unroll
        for (int q = 0; q < 2; ++q) gl2lds16(Ag + offA[q] + kof, Sb + ldsA[q]);
        #pragma unroll
        for (int q = 0; q < 3; ++q) gl2lds16(Wl + offW[q] + kof, Sb + ldsW[q]);
    };

    auto COMPUTE = [&](int slot) {
        const unsigned short* Sa = &lds[slot * 20480];
        const unsigned short* Sw = Sa + 8192;
        bf16x8 af[8];
        #pragma unroll
        for (int t = 0; t < 8; ++t)
            af[t] = *(const bf16x8*)&Sa[(wm + t*16 + l15)*32 + crd*8];
        __builtin_amdgcn_s_setprio(1);
        #pragma unroll
        for (int g = 0; g < 3; ++g) {
            bf16x8 wf[2];
            #pragma unroll
            for (int t = 0; t < 2; ++t)
                wf[t] = *(const bf16x8*)&Sw[(g*128 + wn + t*16 + l15)*32 + crd*8];
            #pragma unroll
            for (int tm = 0; tm < 8; ++tm)
                #pragma unroll
                for (int tn = 0; tn < 2; ++tn)
                    acc[g][tm][tn] = __builtin_amdgcn_mfma_f32_16x16x32_bf16(af[tm], wf[tn], acc[g][tm][tn], 0, 0, 0);
        }
        __builtin_amdgcn_s_setprio(0);
    };

    const int niter = K >> 5;                 // 32 K-tiles

    // prologue: tiles 0,1 in flight
    STAGE(0, 0);
    STAGE(1, 1);

    // main loop: counted vmcnt(10) = tiles t+1,t+2 (5 loads each) stay in flight
    for (int t = 0; t < niter - 2; ++t) {
        STAGE(t + 2, (t + 2) & 3);
        asm volatile("s_waitcnt vmcnt(10) lgkmcnt(0)" ::: "memory");
        __builtin_amdgcn_s_barrier();
        asm volatile("" ::: "memory");
        COMPUTE(t & 3);
    }
    // tail: drain 5 -> 0
    asm volatile("s_waitcnt vmcnt(5) lgkmcnt(0)" ::: "memory");
    __builtin_amdgcn_s_barrier();
    asm volatile("" ::: "memory");
    COMPUTE((niter - 2) & 3);
    asm volatile("s_waitcnt vmcnt(0) lgkmcnt(0)" ::: "memory");
    __builtin_amdgcn_s_barrier();
    asm volatile("" ::: "memory");
    COMPUTE((niter - 1) & 3);

    // ---- epilogue: gate math + packed u32 (fp|add<<16) + fused chunk summaries ----
    const int colc0 = cb*128 + wn + l15;
    const int colc1 = colc0 + 16;
    float bf0 = bias3[colc0],      bf1 = bias3[colc1];
    float bi0 = bias3[Hq+colc0],   bi1 = bias3[Hq+colc1];
    float bh0 = bias3[2*Hq+colc0], bh1 = bias3[2*Hq+colc1];

    const int b_ = bm >> 2;                       // batch (1024 rows = 4 blocks)
    const int chunkBase = (bm & 3) * 8 + (wm >> 5);

    #pragma unroll
    for (int cc = 0; cc < 4; ++cc) {
        float sP[2][2] = {{1.f,1.f},{1.f,1.f}};   // [tn][seg]
        float sA[2][2] = {{0.f,0.f},{0.f,0.f}};
        #pragma unroll
        for (int sg = 0; sg < 2; ++sg) {
            int tm   = cc*2 + sg;
            int row0 = bm*256 + wm + tm*16 + quad*4;
            #pragma unroll
            for (int r = 0; r < 4; ++r) {
                #pragma unroll
                for (int tn = 0; tn < 2; ++tn) {
                    float bfv_ = tn ? bf1 : bf0;
                    float biv_ = tn ? bi1 : bi0;
                    float bhv_ = tn ? bh1 : bh0;
                    int   col  = tn ? colc1 : colc0;
                    float f  = sigm(acc[0][tm][tn][r] + bfv_);
                    float i  = sigm(acc[1][tm][tn][r] + biv_);
                    float ht = acc[2][tm][tn][r] + bhv_;
                    float rd = 1.f / (f + i);
                    unsigned short ufp = f2bf(f * rd);
                    unsigned short uad = f2bf(i * rd * ht);
                    FA[(size_t)(row0 + r) * Hq + col] =
                        (unsigned int)ufp | ((unsigned int)uad << 16);
                    float fpq = bf2f((unsigned int)ufp);
                    float adq = bf2f((unsigned int)uad);
                    sA[tn][sg] = fpq * sA[tn][sg] + adq;   // time order: r ascending
                    sP[tn][sg] *= fpq;
                }
            }
        }
        // chunk total = compose 8 segments in time order:
        // (seg0: quad0..3) then (seg1: quad0..3). Ordered cross-quad scan via
        // shfl_up (shuffles outside divergence; compose guarded by quad).
        int chunk  = chunkBase + cc;
        int oibase = (b_*NCc + chunk) * Hq;
        #pragma unroll
        for (int tn = 0; tn < 2; ++tn) {
            float P0 = sP[tn][0], A0 = sA[tn][0];
            float P1 = sP[tn][1], A1 = sA[tn][1];
            float pp, aa;
            pp = __shfl_up(P0, 16); aa = __shfl_up(A0, 16);
            if (quad >= 1) { A0 = P0*aa + A0; P0 = P0*pp; }
            pp = __shfl_up(P0, 32); aa = __shfl_up(A0, 32);
            if (quad >= 2) { A0 = P0*aa + A0; P0 = P0*pp; }
            pp = __shfl_up(P1, 16); aa = __shfl_up(A1, 16);
            if (quad >= 1) { A1 = P1*aa + A1; P1 = P1*pp; }
            pp = __shfl_up(P1, 32); aa = __shfl_up(A1, 32);
            if (quad >= 2) { A1 = P1*aa + A1; P1 = P1*pp; }
            float P0t = __shfl(P0, 48 + l15); float A0t = __shfl(A0, 48 + l15);
            float P1t = __shfl(P1, 48 + l15); float A1t = __shfl(A1, 48 + l15);
            if (quad == 0) {
                int col = tn ? colc1 : colc0;
                Ps[oibase + col]   = P1t * P0t;
                Asum[oibase + col] = P1t * A0t + A1t;
            }
        }
    }
}

// ---------------- plain bf16 GEMM (used for KV projection) ----------------
// Round-3/5-verified ring-4 counted-vmcnt pipeline (slot 16KB, ring 64KB ->
// 2 blocks/CU; 4 loads/tile/thread -> vmcnt(8)).
__global__ __launch_bounds__(256, 2)
void gemm_bt_kernel(const unsigned short* __restrict__ A, const unsigned short* __restrict__ W,
                    const float* __restrict__ bias, unsigned short* __restrict__ C,
                    int N, int K, int nbn)
{
    __shared__ unsigned short lds[4 * 8192];    // 64 KB: 4 slots x (A 4096 + W 4096 shorts)
    const int tid  = threadIdx.x;

    const int lid = blockIdx.x;
    const int xcd = lid & 7;
    const int s   = lid >> 3;
    const int bm  = xcd * 16 + s / nbn;
    const int bn  = s % nbn;

    const int wid  = tid >> 6, lane = tid & 63;
    const int wm   = (wid >> 1) * 64, wn = (wid & 1) * 64;
    const int l15  = lane & 15, quad = lane >> 4;

    const unsigned short* Ag = A + (size_t)(bm*128) * K;
    const unsigned short* Wg = W + (size_t)(bn*128) * K;

    const int r0   = wid*32 + (lane >> 2);
    const int cst  = (lane & 3) ^ ((r0 >> 1) & 3);
    const int g0   = r0 * K + cst*8;
    const int g1   = (r0 + 16) * K + cst*8;
    const int lofs0 = wid*1024;
    const int lofs1 = wid*1024 + 512;

    const int crd = quad ^ ((l15 >> 1) & 3);

    f32x4 acc[4][4] = {};

    auto STAGE = [&](int kt, int slot) {
        const int kof = kt << 5;
        unsigned short* Sb = &lds[slot * 8192];
        gl2lds16(Ag + g0 + kof, Sb + lofs0);
        gl2lds16(Ag + g1 + kof, Sb + lofs1);
        gl2lds16(Wg + g0 + kof, Sb + 4096 + lofs0);
        gl2lds16(Wg + g1 + kof, Sb + 4096 + lofs1);
    };

    auto COMPUTE = [&](int slot) {
        const unsigned short* Sa = &lds[slot * 8192];
        const unsigned short* Sw = Sa + 4096;
        bf16x8 af[4], wf[4];
        #pragma unroll
        for (int t = 0; t < 4; ++t) {
            af[t] = *(const bf16x8*)&Sa[(wm + t*16 + l15)*32 + crd*8];
            wf[t] = *(const bf16x8*)&Sw[(wn + t*16 + l15)*32 + crd*8];
        }
        __builtin_amdgcn_s_setprio(1);
        #pragma unroll
        for (int tm = 0; tm < 4; ++tm)
            #pragma unroll
            for (int tn = 0; tn < 4; ++tn)
                acc[tm][tn] = __builtin_amdgcn_mfma_f32_16x16x32_bf16(af[tm], wf[tn], acc[tm][tn], 0, 0, 0);
        __builtin_amdgcn_s_setprio(0);
    };

    const int niter = K >> 5;

    STAGE(0, 0);
    STAGE(1, 1);

    for (int it = 0; it < niter - 2; ++it) {
        STAGE(it + 2, (it + 2) & 3);
        asm volatile("s_waitcnt vmcnt(8) lgkmcnt(0)" ::: "memory");
        __builtin_amdgcn_s_barrier();
        asm volatile("" ::: "memory");
        COMPUTE(it & 3);
    }
    asm volatile("s_waitcnt vmcnt(4) lgkmcnt(0)" ::: "memory");
    __builtin_amdgcn_s_barrier();
    asm volatile("" ::: "memory");
    COMPUTE((niter - 2) & 3);
    asm volatile("s_waitcnt vmcnt(0) lgkmcnt(0)" ::: "memory");
    __builtin_amdgcn_s_barrier();
    asm volatile("" ::: "memory");
    COMPUTE((niter - 1) & 3);

    #pragma unroll
    for (int tm = 0; tm < 4; ++tm) {
        int row0 = bm*128 + wm + tm*16 + quad*4;
        #pragma unroll
        for (int tn = 0; tn < 4; ++tn) {
            int col = bn*128 + wn + tn*16 + l15;
            float bv = bias[col];
            #pragma unroll
            for (int r = 0; r < 4; ++r)
                C[(size_t)(row0 + r) * N + col] = f2bf(acc[tm][tn][r] + bv);
        }
    }
}

// ---------------- chunk-level prefix (pass B) ----------------
__global__ void scan_base_kernel(const float* __restrict__ Ps, const float* __restrict__ Asum,
                                 float* __restrict__ Hb) {
    int t = blockIdx.x * 256 + threadIdx.x;  // B*H = 16384
    int b = t >> 10, j = t & 1023;
    float h = 0.f;
    for (int c = 0; c < NCc; ++c) {
        int idx = (b*NCc + c)*Hq + j;
        Hb[idx] = h;
        h = Ps[idx] * h + Asum[idx];
    }
}

// ---------------- pass C: read packed FPAD, scan with correct init, write bf16 h ----
__global__ __launch_bounds__(256)
void scan_out_kernel(const unsigned int* __restrict__ FA,
                     const float* __restrict__ Hb, unsigned short* __restrict__ Ho) {
    int bid = blockIdx.x;                    // B*NC*2 = 1024
    int tid = threadIdx.x;
    int b = bid >> 6; int r = bid & 63; int chunk = r >> 1; int jb = r & 1;
    int j = jb*512 + tid*2;
    size_t base = ((size_t)(b*Sq + chunk*CTc)) * Hq + j;
    int oi = (b*NCc + chunk)*Hq + j;
    float h0 = Hb[oi], h1 = Hb[oi+1];
    for (int s = 0; s < CTc; ++s) {
        size_t ro = base + (size_t)s * Hq;
        uint2 v = *(const uint2*)(FA + ro);
        h0 = bf2f(v.x & 0xffffu) * h0 + bf2f(v.x >> 16);
        h1 = bf2f(v.y & 0xffffu) * h1 + bf2f(v.y >> 16);
        unsigned int packed = (unsigned int)f2bf(h0) | ((unsigned int)f2bf(h1) << 16);
        *(unsigned int*)(Ho + ro) = packed;
    }
}

// ---------------- extract last-position activations as fp32 ----------------
__global__ void xlast_kernel(const unsigned short* __restrict__ act, float* __restrict__ xl) {
    int i = blockIdx.x * 256 + threadIdx.x;  // B*H
    int b = i >> 10, j = i & 1023;
    xl[i] = bf2f((unsigned int)act[((size_t)(b*Sq + Sq-1)) * Hq + j]);
}

// ---------------- wave-per-row GEMV: out[b,n] = W[n,:].x[b,:] + bias[n] (+resid[b,n]) ----------------
__global__ __launch_bounds__(256)
void gemv_kernel(const float* __restrict__ W, const float* __restrict__ xv,
                 const float* __restrict__ bias, const float* __restrict__ resid,
                 float* __restrict__ out, int N) {
    int b = blockIdx.x;
    int w = threadIdx.x >> 6, lane = threadIdx.x & 63;
    int n = blockIdx.y*4 + w;
    __shared__ float xs[Hq];
    *(float4*)&xs[threadIdx.x*4] = *(const float4*)&xv[(size_t)b*Hq + threadIdx.x*4];
    __syncthreads();
    const float4* wr = (const float4*)(W + (size_t)n * Hq);
    float a = 0.f;
    #pragma unroll
    for (int c = 0; c < 4; ++c) {
        float4 wv = wr[c*64 + lane];
        float4 x4 = *(const float4*)&xs[c*256 + lane*4];
        a += wv.x*x4.x + wv.y*x4.y + wv.z*x4.z + wv.w*x4.w;
    }
    #pragma unroll
    for (int st = 32; st > 0; st >>= 1) a += __shfl_xor(a, st, 64);
    if (lane == 0) out[(size_t)b*N + n] = a + bias[n] + (resid ? resid[(size_t)b*Hq + n] : 0.f);
}

// ---------------- attention for the single last-position query ----------------
__global__ __launch_bounds__(1024)
void attn_kernel(const unsigned short* __restrict__ KV,
                 const float* __restrict__ q, float* __restrict__ o) {
    int b = blockIdx.x >> 3, nh = blockIdx.x & 7;
    int tid = threadIdx.x;
    __shared__ float qs[DHq];
    __shared__ float p[Sq];
    __shared__ float redw[16];
    __shared__ float red2[16*DHq];
    if (tid < DHq) qs[tid] = q[b*Hq + nh*DHq + tid] * 0.08838834764831845f;
    __syncthreads();

    const int g = tid >> 4, l = tid & 15;
    const unsigned short* Kb = KV + (size_t)b*Sq*2048 + nh*DHq;
    float lmax = -1e30f;
    #pragma unroll 4
    for (int it = 0; it < 16; ++it) {
        int s = it*64 + g;
        union { uint4 v; unsigned short u[8]; } kk;
        kk.v = *(const uint4*)(Kb + (size_t)s*2048 + l*8);
        float a = 0.f;
        #pragma unroll
        for (int j = 0; j < 8; ++j) a += bf2f((unsigned int)kk.u[j]) * qs[l*8 + j];
        a += __shfl_xor(a, 1, 16);
        a += __shfl_xor(a, 2, 16);
        a += __shfl_xor(a, 4, 16);
        a += __shfl_xor(a, 8, 16);
        if (l == 0) p[s] = a;
        lmax = fmaxf(lmax, a);
    }
    #pragma unroll
    for (int st = 32; st > 0; st >>= 1) lmax = fmaxf(lmax, __shfl_xor(lmax, st, 64));
    if ((tid & 63) == 0) redw[tid >> 6] = lmax;
    __syncthreads();
    float mx = redw[0];
    #pragma unroll
    for (int i = 1; i < 16; ++i) mx = fmaxf(mx, redw[i]);

    float e = __expf(p[tid] - mx);
    float ls = e;
    #pragma unroll
    for (int st = 32; st > 0; st >>= 1) ls += __shfl_xor(ls, st, 64);
    __syncthreads();
    p[tid] = e;
    if ((tid & 63) == 0) redw[tid >> 6] = ls;
    __syncthreads();
    float ssum = 0.f;
    #pragma unroll
    for (int i = 0; i < 16; ++i) ssum += redw[i];
    float inv = 1.f / ssum;

    int d2 = (tid & 63) * 2, sb = tid >> 6;
    const unsigned short* Vb = KV + (size_t)b*Sq*2048 + 1024 + nh*DHq + d2;
    float a0 = 0.f, a1 = 0.f;
    for (int s = sb*64; s < sb*64 + 64; ++s) {
        unsigned int vv = *(const unsigned int*)(Vb + (size_t)s*2048);
        float pw = p[s];
        a0 += pw * bf2f(vv & 0xffffu);
        a1 += pw * bf2f(vv >> 16);
    }
    red2[sb*DHq + d2] = a0;
    red2[sb*DHq + d2 + 1] = a1;
    __syncthreads();
    if (tid < DHq) {
        float a = 0.f;
        #pragma unroll
        for (int i = 0; i < 16; ++i) a += red2[i*DHq + tid];
        o[b*Hq + nh*DHq + tid] = a * inv;
    }
}

extern "C" void kernel_launch(void* const* d_in, const int* in_sizes, int n_in,
                              void* d_out, int out_size, void* d_ws, size_t ws_size,
                              hipStream_t stream) {
    const float* x        = (const float*)d_in[0];
    const float* Wf       = (const float*)d_in[1];
    const float* bfv      = (const float*)d_in[2];
    const float* Wi       = (const float*)d_in[3];
    const float* biv      = (const float*)d_in[4];
    const float* Wh       = (const float*)d_in[5];
    const float* bhv      = (const float*)d_in[6];
    const float* in_proj_w= (const float*)d_in[7];
    const float* in_proj_b= (const float*)d_in[8];
    const float* out_w    = (const float*)d_in[9];
    const float* out_b    = (const float*)d_in[10];
    const float* fc_w     = (const float*)d_in[11];
    const float* fc_b     = (const float*)d_in[12];
    float* outp = (float*)d_out;

    // workspace carve (~130 MB)
    char* p = (char*)d_ws;
    auto alloc = [&](size_t bytes) -> void* {
        void* r = (void*)p; p += (bytes + 255) & ~(size_t)255; return r;
    };
    unsigned short* Wcat = (unsigned short*)alloc((size_t)Lq*3*HHq*2);  // 24 MB
    unsigned short* Wkv  = (unsigned short*)alloc((size_t)2048*Hq*2);   //  4 MB
    float*          Bias3= (float*)alloc((size_t)Lq*3*Hq*4);            // 48 KB
    unsigned short* actA = (unsigned short*)alloc((size_t)Mq*Hq*2);     // 32 MB
    unsigned short* actB = (unsigned short*)alloc((size_t)Mq*Hq*2);     // 32 MB
    unsigned int*   FAg  = (unsigned int*)alloc((size_t)Mq*Hq*4);       // 64 MB packed (fp,add)
    float* Ps   = (float*)alloc((size_t)Bq*NCc*Hq*4);                   //  2 MB
    float* Asum = (float*)alloc((size_t)Bq*NCc*Hq*4);                   //  2 MB
    float* Hb   = (float*)alloc((size_t)Bq*NCc*Hq*4);                   //  2 MB
    unsigned short* KV = (unsigned short*)FAg;  // alias 64 MB, used only after layers done
    float* xl   = (float*)alloc((size_t)Bq*Hq*4);
    float* qbuf = (float*)alloc((size_t)Bq*Hq*4);
    float* obuf = (float*)alloc((size_t)Bq*Hq*4);
    float* rbuf = (float*)alloc((size_t)Bq*Hq*4);

    // --- conversions ---
    cvt_kernel<<<Mq*Hq/256, 256, 0, stream>>>(x, actA, Mq*Hq);
    cvtW_kernel<<<Lq*3*HHq/256, 256, 0, stream>>>(Wf, Wi, Wh, Wcat);
    cvt_kernel<<<2048*Hq/256, 256, 0, stream>>>(in_proj_w + (size_t)Hq*Hq, Wkv, 2048*Hq);
    bias3_kernel<<<(Lq*3*Hq)/256, 256, 0, stream>>>(bfv, biv, bhv, Bias3);

    // --- minLSTM layers (scan_sum fused into gemm_gate epilogue) ---
    unsigned short* cur = actA;
    unsigned short* nxt = actB;
    for (int l = 0; l < Lq; ++l) {
        gemm_gate_kernel<<<(Mq/256)*(Hq/128), 512, 0, stream>>>(
            cur, Wcat + (size_t)l*3*HHq, Bias3 + l*3*Hq, FAg, Ps, Asum);
        scan_base_kernel<<<Bq*Hq/256, 256, 0, stream>>>(Ps, Asum, Hb);
        scan_out_kernel<<<Bq*NCc*2, 256, 0, stream>>>(FAg, Hb, nxt);
        unsigned short* t = cur; cur = nxt; nxt = t;
    }

    // --- attention (only last-position query matters) ---
    gemm_bt_kernel<<<(Mq/128)*(2048/128), 256, 0, stream>>>(
        cur, Wkv, in_proj_b + Hq, KV, 2048, Hq, 2048/128);
    xlast_kernel<<<Bq*Hq/256, 256, 0, stream>>>(cur, xl);
    gemv_kernel<<<dim3(Bq, Hq/4), 256, 0, stream>>>(in_proj_w, xl, in_proj_b, nullptr, qbuf, Hq);
    attn_kernel<<<Bq*NHq, 1024, 0, stream>>>(KV, qbuf, obuf);
    gemv_kernel<<<dim3(Bq, Hq/4), 256, 0, stream>>>(out_w, obuf, out_b, xl, rbuf, Hq);
    gemv_kernel<<<dim3(Bq, Oq/4), 256, 0, stream>>>(fc_w, rbuf, fc_b, nullptr, outp, Oq);
}